// Round 13
// baseline (696.923 us; speedup 1.0000x reference)
//
#include <hip/hip_runtime.h>
#include <math.h>

#define NUM_FREQS   64
#define NUM_BINS    128
#define NUM_QUERIES 32768
#define HEAD_DIM    128
#define EPS         1e-8f
#define NQB         16   // queries per block (4 waves x 4 j each)

// ---------------------------------------------------------------------------
// Fused prep: blocks [0,128) normalize Q -> Qri {qr,qi} + Qm planes;
// blocks [128,160) pack probe constants for the expanded-distance form:
//   probeA[f*128+b] = { -2*Pr, -2*Pi, Pr^2+Pi^2, -softplus(w) }
//   probeM[f*128+b] = mw
// (eps is carried inside qm^2 = qr^2+qi^2+eps, so C'' needs no eps.)
// ---------------------------------------------------------------------------
__global__ void prep_fused(const float* __restrict__ Q,
                           const float* __restrict__ rp,
                           const float* __restrict__ wraw,
                           const float* __restrict__ mw,
                           float2* __restrict__ Qri,
                           float*  __restrict__ Qm,
                           float4* __restrict__ probeA,
                           float*  __restrict__ probeM) {
    const int bid = blockIdx.x;
    const int tid = threadIdx.x;
    if (bid < 128) {
        int q = bid * 256 + tid;
        const float4* Qrow = reinterpret_cast<const float4*>(Q + (size_t)q * HEAD_DIM);
        float4 buf[32];
        float s = 0.0f;
        #pragma unroll
        for (int i = 0; i < 32; i++) {
            float4 v = Qrow[i];
            buf[i] = v;
            s = fmaf(v.x, v.x, fmaf(v.y, v.y, fmaf(v.z, v.z, fmaf(v.w, v.w, s))));
        }
        float inv = 1.0f / (__builtin_amdgcn_sqrtf(s) + EPS);
        #pragma unroll
        for (int i = 0; i < 16; i++) {
            float4 r  = buf[i];
            float4 im = buf[16 + i];
            float rr[4] = { r.x,  r.y,  r.z,  r.w  };
            float ii[4] = { im.x, im.y, im.z, im.w };
            #pragma unroll
            for (int k = 0; k < 4; k++) {
                float qr = rr[k] * inv;
                float qi = ii[k] * inv;
                float qm = __builtin_amdgcn_sqrtf(fmaf(qr, qr, fmaf(qi, qi, EPS)));
                int f = 4 * i + k;
                Qri[(size_t)f * NUM_QUERIES + q] = make_float2(qr, qi);  // coalesced
                Qm [(size_t)f * NUM_QUERIES + q] = qm;
            }
        }
    } else {
        int idx = (bid - 128) * 256 + tid;       // idx = f*128 + b
        if (idx >= NUM_FREQS * NUM_BINS) return;
        int f = idx >> 7;
        int b = idx & 127;
        float pr = rp[b * HEAD_DIM + f];
        float pi = rp[b * HEAD_DIM + NUM_FREQS + f];
        float w  = wraw[b * NUM_FREQS + f];
        float sp = fmaxf(w, 0.0f) + log1pf(expf(-fabsf(w)));   // stable softplus
        probeA[idx] = make_float4(-2.0f * pr, -2.0f * pi,
                                  fmaf(pr, pr, pi * pi), -sp);
        probeM[idx] = mw[b * NUM_FREQS + f];
    }
}

// ---------------------------------------------------------------------------
// Main: block = 256 threads (4 waves); block owns 16 queries; wave w owns
// j in [4w, 4w+4); lane covers bins (lane, lane+64) -> 8 outputs per lane.
// Expanded distance: s = C'' + qm^2 - 2Pr*qr - 2Pi*qi (5 fma + 1 sqrt per
// output incl. magnitude term). Grid = 2048 blocks = 8 blocks/CU (32 w/CU).
// WAVE STAGGER: each wave starts its f-loop at f0 = ((wave+block)&3)*16 and
// wraps at 64 -> waves de-phase, VMEM bursts spread out, VALU stays fed.
// LDS row strides: sri = 8 float4 / f-row, sqm = 4 float4 / f-row.
// ---------------------------------------------------------------------------
__global__ __launch_bounds__(256, 8) void main_kernel(
        const float4* __restrict__ probeA,
        const float*  __restrict__ probeM,
        const float2* __restrict__ Qri,
        const float*  __restrict__ Qm,
        const float*  __restrict__ bias,
        float*        __restrict__ out) {
    __shared__ float2 sri[NUM_FREQS][NQB];   // 8 KB  [f][j] {qr,qi}
    __shared__ float  sqm[NUM_FREQS][NQB];   // 4 KB  [f][j] qm

    const int tid   = threadIdx.x;
    const int qbase = blockIdx.x * NQB;

    // Stage q-panel: 512 + 256 float4 stores, 3 per thread, coalesced.
    #pragma unroll
    for (int i = 0; i < 3; i++) {
        int idx = i * 256 + tid;
        if (idx < 512) {                       // sri: f = idx>>3, chunk = idx&7
            int f = idx >> 3, c = idx & 7;
            reinterpret_cast<float4*>(&sri[f][0])[c] =
                reinterpret_cast<const float4*>(Qri + (size_t)f * NUM_QUERIES + qbase)[c];
        } else {                               // sqm
            int t2 = idx - 512;
            int f = t2 >> 2, c = t2 & 3;
            reinterpret_cast<float4*>(&sqm[f][0])[c] =
                reinterpret_cast<const float4*>(Qm + (size_t)f * NUM_QUERIES + qbase)[c];
        }
    }
    __syncthreads();

    const int lane = tid & 63;
    const int wave = tid >> 6;
    const int jb   = wave * 4;               // this wave's j-chunk base
    const int f0   = ((wave + blockIdx.x) & 3) << 4;   // 0,16,32,48 stagger

    float b0 = bias[lane];                   // hoisted epilogue loads
    float b1 = bias[64 + lane];

    float acc0[4], acc1[4];
    #pragma unroll
    for (int p = 0; p < 4; p++) { acc0[p] = 0.0f; acc1[p] = 0.0f; }

    // Walking pointers (reset at the f=64 wrap).
    // sri f-row = 16 float2 = 8 float4; this wave's j-chunk = +2 float4.
    // sqm f-row = 16 float  = 4 float4; this wave's j-chunk = +1 float4.
    const float4* pA = probeA + f0 * NUM_BINS + lane;       // +128/f
    const float*  pM = probeM + f0 * NUM_BINS + lane;
    const float4* arBase = reinterpret_cast<const float4*>(sri) + wave * 2;
    const float4* amBase = reinterpret_cast<const float4*>(sqm) + wave;
    const float4* ar = arBase + f0 * 8;
    const float4* am = amBase + f0 * 4;

    int fcur = f0;
    for (int g = 0; g < 16; ++g) {
        #pragma unroll
        for (int u = 0; u < 4; ++u) {
            float4 P0 = pA[u * NUM_BINS];        // {-2Pr,-2Pi,C'',wz} bin=lane
            float4 P1 = pA[u * NUM_BINS + 64];   //                    bin=lane+64
            float  w0 = pM[u * NUM_BINS];
            float  w1 = pM[u * NUM_BINS + 64];
            float4 r01 = ar[u * 8];              // {qr,qi} j0,j1
            float4 r23 = ar[u * 8 + 1];          // {qr,qi} j2,j3
            float4 qm4 = am[u * 4];              // qm j0..3

            const float qrv[4] = { r01.x, r01.z, r23.x, r23.z };
            const float qiv[4] = { r01.y, r01.w, r23.y, r23.w };
            const float qmv[4] = { qm4.x, qm4.y, qm4.z, qm4.w };

            #pragma unroll
            for (int p = 0; p < 4; p++) {
                float qr = qrv[p], qi = qiv[p], qm = qmv[p];
                {   // bin = lane
                    float a = fmaf(qm, qm, P0.z);
                    a = fmaf(P0.x, qr, a);
                    a = fmaf(P0.y, qi, a);
                    float d = __builtin_amdgcn_sqrtf(a);
                    acc0[p] = fmaf(d, P0.w, fmaf(qm, w0, acc0[p]));
                }
                {   // bin = lane + 64
                    float a = fmaf(qm, qm, P1.z);
                    a = fmaf(P1.x, qr, a);
                    a = fmaf(P1.y, qi, a);
                    float d = __builtin_amdgcn_sqrtf(a);
                    acc1[p] = fmaf(d, P1.w, fmaf(qm, w1, acc1[p]));
                }
            }
        }
        pA += 4 * NUM_BINS; pM += 4 * NUM_BINS; ar += 32; am += 16;
        fcur += 4;
        if (fcur == NUM_FREQS) {                 // wave-uniform wrap
            fcur = 0;
            pA = probeA + lane;
            pM = probeM + lane;
            ar = arBase;
            am = amBase;
        }
    }

    #pragma unroll
    for (int p = 0; p < 4; p++) {
        size_t row = (size_t)(qbase + jb + p) * NUM_BINS;
        out[row + lane]      = acc0[p] + b0;     // coalesced
        out[row + 64 + lane] = acc1[p] + b1;     // coalesced
    }
}

// ---------------------------------------------------------------------------
// Fallback (only if ws_size is too small): fully self-contained, slower.
// ---------------------------------------------------------------------------
__global__ void fallback_kernel(const float* __restrict__ Q,
                                const float* __restrict__ rp,
                                const float* __restrict__ wraw,
                                const float* __restrict__ mw,
                                const float* __restrict__ bias,
                                float* __restrict__ out) {
    __shared__ float qn[HEAD_DIM];
    __shared__ float qmag[NUM_FREQS];
    __shared__ float red[NUM_BINS];
    const int t = threadIdx.x;
    const int q = blockIdx.x;

    float v = Q[(size_t)q * HEAD_DIM + t];
    red[t] = v * v;
    __syncthreads();
    for (int s = 64; s > 0; s >>= 1) {
        if (t < s) red[t] += red[t + s];
        __syncthreads();
    }
    float inv = 1.0f / (__builtin_amdgcn_sqrtf(red[0]) + EPS);
    qn[t] = v * inv;
    __syncthreads();
    if (t < NUM_FREQS) {
        float a = qn[t], c = qn[t + NUM_FREQS];
        qmag[t] = __builtin_amdgcn_sqrtf(fmaf(a, a, fmaf(c, c, EPS)));
    }
    __syncthreads();

    const int b = t;
    float acc = 0.0f;
    for (int f = 0; f < NUM_FREQS; f++) {
        float pr = rp[(size_t)b * HEAD_DIM + f];
        float pi = rp[(size_t)b * HEAD_DIM + NUM_FREQS + f];
        float w  = wraw[(size_t)b * NUM_FREQS + f];
        float ew = -(fmaxf(w, 0.0f) + log1pf(expf(-fabsf(w))));
        float er = pr - qn[f];
        float ei = pi - qn[f + NUM_FREQS];
        float d  = __builtin_amdgcn_sqrtf(fmaf(er, er, fmaf(ei, ei, EPS)));
        acc = fmaf(d, ew, fmaf(qmag[f], mw[(size_t)b * NUM_FREQS + f], acc));
    }
    out[(size_t)q * NUM_BINS + b] = acc + bias[b];
}

// ---------------------------------------------------------------------------
extern "C" void kernel_launch(void* const* d_in, const int* in_sizes, int n_in,
                              void* d_out, int out_size, void* d_ws, size_t ws_size,
                              hipStream_t stream) {
    const float* Q    = (const float*)d_in[0];
    const float* rp   = (const float*)d_in[1];
    const float* wraw = (const float*)d_in[2];
    const float* mw   = (const float*)d_in[3];
    const float* bias = (const float*)d_in[4];
    float* out = (float*)d_out;

    const size_t pABytes  = (size_t)NUM_FREQS * NUM_BINS * sizeof(float4);    // 128 KiB
    const size_t pMBytes  = (size_t)NUM_FREQS * NUM_BINS * sizeof(float);     //  32 KiB
    const size_t qriBytes = (size_t)NUM_FREQS * NUM_QUERIES * sizeof(float2); //  16 MiB
    const size_t qmBytes  = (size_t)NUM_FREQS * NUM_QUERIES * sizeof(float);  //   8 MiB
    const size_t need     = pABytes + pMBytes + qriBytes + qmBytes;           // ~24.2 MiB

    if (ws_size >= need) {
        float4* probeA = (float4*)d_ws;
        float*  probeM = (float*)((char*)d_ws + pABytes);
        float2* Qri    = (float2*)((char*)d_ws + pABytes + pMBytes);
        float*  Qm     = (float*)((char*)d_ws + pABytes + pMBytes + qriBytes);

        hipLaunchKernelGGL(prep_fused, dim3(128 + 32), dim3(256), 0, stream,
                           Q, rp, wraw, mw, Qri, Qm, probeA, probeM);
        hipLaunchKernelGGL(main_kernel, dim3(NUM_QUERIES / NQB), dim3(256), 0,
                           stream, probeA, probeM, Qri, Qm, bias, out);
    } else {
        hipLaunchKernelGGL(fallback_kernel, dim3(NUM_QUERIES), dim3(NUM_BINS), 0,
                           stream, Q, rp, wraw, mw, bias, out);
    }
}

// Round 14
// 76.084 us; speedup vs baseline: 9.1600x; 9.1600x over previous
//
#include <hip/hip_runtime.h>
#include <math.h>

#define NUM_FREQS   64
#define NUM_BINS    128
#define NUM_QUERIES 32768
#define HEAD_DIM    128
#define EPS         1e-8f
#define NQB         16   // queries per block (4 waves x 4 j each)

// ---------------------------------------------------------------------------
// Fused prep: blocks [0,128) normalize Q -> Qri {qr,qi} + Qm planes;
// blocks [128,160) pack probe constants for the expanded-distance form:
//   probeA[f*128+b] = { -2*Pr, -2*Pi, Pr^2+Pi^2, -softplus(w) }
//   probeM[f*128+b] = mw
// (eps is carried inside qm^2 = qr^2+qi^2+eps, so C'' needs no eps.)
// ---------------------------------------------------------------------------
__global__ void prep_fused(const float* __restrict__ Q,
                           const float* __restrict__ rp,
                           const float* __restrict__ wraw,
                           const float* __restrict__ mw,
                           float2* __restrict__ Qri,
                           float*  __restrict__ Qm,
                           float4* __restrict__ probeA,
                           float*  __restrict__ probeM) {
    const int bid = blockIdx.x;
    const int tid = threadIdx.x;
    if (bid < 128) {
        int q = bid * 256 + tid;
        const float4* Qrow = reinterpret_cast<const float4*>(Q + (size_t)q * HEAD_DIM);
        float4 buf[32];
        float s = 0.0f;
        #pragma unroll
        for (int i = 0; i < 32; i++) {
            float4 v = Qrow[i];
            buf[i] = v;
            s = fmaf(v.x, v.x, fmaf(v.y, v.y, fmaf(v.z, v.z, fmaf(v.w, v.w, s))));
        }
        float inv = 1.0f / (__builtin_amdgcn_sqrtf(s) + EPS);
        #pragma unroll
        for (int i = 0; i < 16; i++) {
            float4 r  = buf[i];
            float4 im = buf[16 + i];
            float rr[4] = { r.x,  r.y,  r.z,  r.w  };
            float ii[4] = { im.x, im.y, im.z, im.w };
            #pragma unroll
            for (int k = 0; k < 4; k++) {
                float qr = rr[k] * inv;
                float qi = ii[k] * inv;
                float qm = __builtin_amdgcn_sqrtf(fmaf(qr, qr, fmaf(qi, qi, EPS)));
                int f = 4 * i + k;
                Qri[(size_t)f * NUM_QUERIES + q] = make_float2(qr, qi);  // coalesced
                Qm [(size_t)f * NUM_QUERIES + q] = qm;
            }
        }
    } else {
        int idx = (bid - 128) * 256 + tid;       // idx = f*128 + b
        if (idx >= NUM_FREQS * NUM_BINS) return;
        int f = idx >> 7;
        int b = idx & 127;
        float pr = rp[b * HEAD_DIM + f];
        float pi = rp[b * HEAD_DIM + NUM_FREQS + f];
        float w  = wraw[b * NUM_FREQS + f];
        float sp = fmaxf(w, 0.0f) + log1pf(expf(-fabsf(w)));   // stable softplus
        probeA[idx] = make_float4(-2.0f * pr, -2.0f * pi,
                                  fmaf(pr, pr, pi * pi), -sp);
        probeM[idx] = mw[b * NUM_FREQS + f];
    }
}

// ---------------------------------------------------------------------------
// Main: block = 256 threads (4 waves); block owns 16 queries; wave w owns
// j in [4w, 4w+4); lane covers bins (lane, lane+64) -> 8 outputs per lane.
// Expanded distance: s = C'' + qm^2 - 2Pr*qr - 2Pi*qi (5 fma + 1 sqrt per
// output incl. magnitude term). Grid = 2048 blocks = 8 blocks/CU (32 w/CU).
// Depth-1 PROBE register prefetch: LDS reads + next-f VMEM loads issued
// before a sched_barrier(0), compute after -> loads can't be re-sunk.
// (f=63 prefetch over-reads into the adjacent ws buffer; never consumed.)
// ---------------------------------------------------------------------------
__global__ __launch_bounds__(256, 8) void main_kernel(
        const float4* __restrict__ probeA,
        const float*  __restrict__ probeM,
        const float2* __restrict__ Qri,
        const float*  __restrict__ Qm,
        const float*  __restrict__ bias,
        float*        __restrict__ out) {
    __shared__ float2 sri[NUM_FREQS][NQB];   // 8 KB  [f][j] {qr,qi}
    __shared__ float  sqm[NUM_FREQS][NQB];   // 4 KB  [f][j] qm

    const int tid   = threadIdx.x;
    const int qbase = blockIdx.x * NQB;

    // Stage q-panel: 512 + 256 float4 stores, 3 per thread, coalesced.
    #pragma unroll
    for (int i = 0; i < 3; i++) {
        int idx = i * 256 + tid;
        if (idx < 512) {                       // sri: f = idx>>3, chunk = idx&7
            int f = idx >> 3, c = idx & 7;
            reinterpret_cast<float4*>(&sri[f][0])[c] =
                reinterpret_cast<const float4*>(Qri + (size_t)f * NUM_QUERIES + qbase)[c];
        } else {                               // sqm
            int t2 = idx - 512;
            int f = t2 >> 2, c = t2 & 3;
            reinterpret_cast<float4*>(&sqm[f][0])[c] =
                reinterpret_cast<const float4*>(Qm + (size_t)f * NUM_QUERIES + qbase)[c];
        }
    }
    __syncthreads();

    const int lane = tid & 63;
    const int wave = tid >> 6;
    const int jb   = wave * 4;               // this wave's j-chunk base

    float b0 = bias[lane];
    float b1 = bias[64 + lane];

    float acc0[4], acc1[4];
    #pragma unroll
    for (int p = 0; p < 4; p++) { acc0[p] = 0.0f; acc1[p] = 0.0f; }

    const float4* pA = probeA + lane;        // advances by 128 per f
    const float*  pM = probeM + lane;

    float4 P0 = pA[0];                       // f = 0 probe row
    float4 P1 = pA[64];
    float  w0 = pM[0];
    float  w1 = pM[64];

    #pragma unroll 4
    for (int f = 0; f < NUM_FREQS; f++) {
        // ---- issue phase: LDS reads for f, VMEM prefetch for f+1 ----
        float4 r01 = *reinterpret_cast<const float4*>(&sri[f][jb]);      // j0,j1
        float4 r23 = *reinterpret_cast<const float4*>(&sri[f][jb + 2]);  // j2,j3
        float4 qm4 = *reinterpret_cast<const float4*>(&sqm[f][jb]);      // qm j0..3
        pA += NUM_BINS; pM += NUM_BINS;
        float4 P0n = pA[0];                  // prefetch next f (vmcnt pipe)
        float4 P1n = pA[64];
        float  w0n = pM[0];
        float  w1n = pM[64];
        __builtin_amdgcn_sched_barrier(0);   // keep loads above the compute

        // ---- compute phase (uses current P0/P1/w0/w1) ----
        const float qrv[4] = { r01.x, r01.z, r23.x, r23.z };
        const float qiv[4] = { r01.y, r01.w, r23.y, r23.w };
        const float qmv[4] = { qm4.x, qm4.y, qm4.z, qm4.w };

        #pragma unroll
        for (int p = 0; p < 4; p++) {
            float qr = qrv[p], qi = qiv[p], qm = qmv[p];
            {   // bin = lane
                float a = fmaf(qm, qm, P0.z);
                a = fmaf(P0.x, qr, a);
                a = fmaf(P0.y, qi, a);
                float d = __builtin_amdgcn_sqrtf(a);
                acc0[p] = fmaf(d, P0.w, fmaf(qm, w0, acc0[p]));
            }
            {   // bin = lane + 64
                float a = fmaf(qm, qm, P1.z);
                a = fmaf(P1.x, qr, a);
                a = fmaf(P1.y, qi, a);
                float d = __builtin_amdgcn_sqrtf(a);
                acc1[p] = fmaf(d, P1.w, fmaf(qm, w1, acc1[p]));
            }
        }

        P0 = P0n; P1 = P1n; w0 = w0n; w1 = w1n;
    }

    #pragma unroll
    for (int p = 0; p < 4; p++) {
        size_t row = (size_t)(qbase + jb + p) * NUM_BINS;
        out[row + lane]      = acc0[p] + b0;     // coalesced
        out[row + 64 + lane] = acc1[p] + b1;     // coalesced
    }
}

// ---------------------------------------------------------------------------
// Fallback (only if ws_size is too small): fully self-contained, slower.
// ---------------------------------------------------------------------------
__global__ void fallback_kernel(const float* __restrict__ Q,
                                const float* __restrict__ rp,
                                const float* __restrict__ wraw,
                                const float* __restrict__ mw,
                                const float* __restrict__ bias,
                                float* __restrict__ out) {
    __shared__ float qn[HEAD_DIM];
    __shared__ float qmag[NUM_FREQS];
    __shared__ float red[NUM_BINS];
    const int t = threadIdx.x;
    const int q = blockIdx.x;

    float v = Q[(size_t)q * HEAD_DIM + t];
    red[t] = v * v;
    __syncthreads();
    for (int s = 64; s > 0; s >>= 1) {
        if (t < s) red[t] += red[t + s];
        __syncthreads();
    }
    float inv = 1.0f / (__builtin_amdgcn_sqrtf(red[0]) + EPS);
    qn[t] = v * inv;
    __syncthreads();
    if (t < NUM_FREQS) {
        float a = qn[t], c = qn[t + NUM_FREQS];
        qmag[t] = __builtin_amdgcn_sqrtf(fmaf(a, a, fmaf(c, c, EPS)));
    }
    __syncthreads();

    const int b = t;
    float acc = 0.0f;
    for (int f = 0; f < NUM_FREQS; f++) {
        float pr = rp[(size_t)b * HEAD_DIM + f];
        float pi = rp[(size_t)b * HEAD_DIM + NUM_FREQS + f];
        float w  = wraw[(size_t)b * NUM_FREQS + f];
        float ew = -(fmaxf(w, 0.0f) + log1pf(expf(-fabsf(w))));
        float er = pr - qn[f];
        float ei = pi - qn[f + NUM_FREQS];
        float d  = __builtin_amdgcn_sqrtf(fmaf(er, er, fmaf(ei, ei, EPS)));
        acc = fmaf(d, ew, fmaf(qmag[f], mw[(size_t)b * NUM_FREQS + f], acc));
    }
    out[(size_t)q * NUM_BINS + b] = acc + bias[b];
}

// ---------------------------------------------------------------------------
extern "C" void kernel_launch(void* const* d_in, const int* in_sizes, int n_in,
                              void* d_out, int out_size, void* d_ws, size_t ws_size,
                              hipStream_t stream) {
    const float* Q    = (const float*)d_in[0];
    const float* rp   = (const float*)d_in[1];
    const float* wraw = (const float*)d_in[2];
    const float* mw   = (const float*)d_in[3];
    const float* bias = (const float*)d_in[4];
    float* out = (float*)d_out;

    const size_t pABytes  = (size_t)NUM_FREQS * NUM_BINS * sizeof(float4);    // 128 KiB
    const size_t pMBytes  = (size_t)NUM_FREQS * NUM_BINS * sizeof(float);     //  32 KiB
    const size_t qriBytes = (size_t)NUM_FREQS * NUM_QUERIES * sizeof(float2); //  16 MiB
    const size_t qmBytes  = (size_t)NUM_FREQS * NUM_QUERIES * sizeof(float);  //   8 MiB
    const size_t need     = pABytes + pMBytes + qriBytes + qmBytes;           // ~24.2 MiB

    if (ws_size >= need) {
        float4* probeA = (float4*)d_ws;
        float*  probeM = (float*)((char*)d_ws + pABytes);
        float2* Qri    = (float2*)((char*)d_ws + pABytes + pMBytes);
        float*  Qm     = (float*)((char*)d_ws + pABytes + pMBytes + qriBytes);

        hipLaunchKernelGGL(prep_fused, dim3(128 + 32), dim3(256), 0, stream,
                           Q, rp, wraw, mw, Qri, Qm, probeA, probeM);
        hipLaunchKernelGGL(main_kernel, dim3(NUM_QUERIES / NQB), dim3(256), 0,
                           stream, probeA, probeM, Qri, Qm, bias, out);
    } else {
        hipLaunchKernelGGL(fallback_kernel, dim3(NUM_QUERIES), dim3(NUM_BINS), 0,
                           stream, Q, rp, wraw, mw, bias, out);
    }
}